// Round 6
// baseline (976.297 us; speedup 1.0000x reference)
//
#include <hip/hip_runtime.h>
#include <hip/hip_bf16.h>

#define HID 64
#define RPW 16   // rows per wave in gemm2_reg

// -------- fused dual GEMM, K-chunked register tiling.
// outa[R][64] = in[R][K] @ Wa[:, coloff:coloff+K]^T
// outb[R][64] = in[R][K] @ Wb[:, coloff:coloff+K]^T
// Wa/Wb row-major (64 x ldw). Each wave owns 16 rows: all 16 row-vectors are
// loaded up front (lane k holds in[j][k]), W streams through registers in
// 16-wide k-chunks (32 VGPRs live), row values broadcast via v_readlane.
// Register budget ~96 VGPRs; __launch_bounds__(256,4) pins allocator to 128
// so nothing spills (R5 failure mode: compiler re-loaded W per row at VGPR=64).
// In-place safe (outa may alias in): all loads precede all stores per wave,
// and rows map 1:1 to waves. `in` deliberately NOT __restrict__.
template <int KC>
__global__ __launch_bounds__(256, 4)
void gemm2_reg(const float* in,
               const float* __restrict__ Wa, const float* __restrict__ Wb,
               float* __restrict__ outa, float* __restrict__ outb,
               int R, int ldw, int coloff) {
    int lane = threadIdx.x & 63;
    int wid = blockIdx.x * (blockDim.x >> 6) + (threadIdx.x >> 6);
    int j0 = wid * RPW;
    if (j0 >= R) return;
    float rv[RPW];
#pragma unroll
    for (int r = 0; r < RPW; ++r) {
        int j = j0 + r;
        rv[r] = (j < R && lane < KC) ? in[(size_t)j * KC + lane] : 0.f;
    }
    float accx[RPW], accy[RPW];
#pragma unroll
    for (int r = 0; r < RPW; ++r) { accx[r] = 0.f; accy[r] = 0.f; }
    const float* pa = Wa + (size_t)lane * ldw + coloff;
    const float* pb = Wb + (size_t)lane * ldw + coloff;
#pragma unroll
    for (int kc = 0; kc < KC; kc += 16) {
        float wx[16], wy[16];
#pragma unroll
        for (int kk = 0; kk < 16; ++kk) { wx[kk] = pa[kc + kk]; wy[kk] = pb[kc + kk]; }
#pragma unroll
        for (int r = 0; r < RPW; ++r) {
#pragma unroll
            for (int kk = 0; kk < 16; ++kk) {
                float s = __int_as_float(__builtin_amdgcn_readlane(
                              __float_as_int(rv[r]), kc + kk));
                accx[r] = fmaf(s, wx[kk], accx[r]);
                accy[r] = fmaf(s, wy[kk], accy[r]);
            }
        }
    }
#pragma unroll
    for (int r = 0; r < RPW; ++r) {
        int j = j0 + r;
        if (j < R) {
            outa[(size_t)j * HID + lane] = accx[r];
            outb[(size_t)j * HID + lane] = accy[r];
        }
    }
}

// ======== CSR build (per edge set, indexed by dst) ========
__global__ void zero_k(int* __restrict__ p, int n) {
    int i = blockIdx.x * 256 + threadIdx.x;
    if (i < n) p[i] = 0;
}

__global__ void zero_f(float* __restrict__ p, int n) {
    int i = blockIdx.x * 256 + threadIdx.x;
    if (i < n) p[i] = 0.f;
}

__global__ void hist_k(const int* __restrict__ dst, int* __restrict__ cnt, int E) {
    int e = blockIdx.x * 256 + threadIdx.x;
    if (e < E) atomicAdd(&cnt[dst[e]], 1);
}

// exclusive scan over n1 = n+1 virtual entries (cnt has n entries; entry n = 0)
__global__ void scan1_k(const int* __restrict__ cnt, int* __restrict__ rs,
                        int* __restrict__ bsum, int n1, int n) {
    __shared__ int wsum[4];
    int t = threadIdx.x;
    int base = blockIdx.x * 1024 + t * 4;
    int v[4]; int s = 0;
#pragma unroll
    for (int i = 0; i < 4; ++i) { int idx = base + i; v[i] = s; s += (idx < n) ? cnt[idx] : 0; }
    int lane = t & 63, wv = t >> 6;
    int x = s;
#pragma unroll
    for (int off = 1; off < 64; off <<= 1) { int y = __shfl_up(x, off, 64); if (lane >= off) x += y; }
    if (lane == 63) wsum[wv] = x;
    __syncthreads();
    int woff = 0;
    for (int w = 0; w < wv; ++w) woff += wsum[w];
    int excl = woff + (x - s);
#pragma unroll
    for (int i = 0; i < 4; ++i) { int idx = base + i; if (idx < n1) rs[idx] = excl + v[i]; }
    if (t == 255) bsum[blockIdx.x] = wsum[0] + wsum[1] + wsum[2] + wsum[3];
}

__global__ void scan2_k(int* __restrict__ bsum, int nb) {
    __shared__ int wsum[4];
    int t = threadIdx.x;
    int s = (t < nb) ? bsum[t] : 0;
    int lane = t & 63, wv = t >> 6;
    int x = s;
#pragma unroll
    for (int off = 1; off < 64; off <<= 1) { int y = __shfl_up(x, off, 64); if (lane >= off) x += y; }
    if (lane == 63) wsum[wv] = x;
    __syncthreads();
    int woff = 0;
    for (int w = 0; w < wv; ++w) woff += wsum[w];
    if (t < nb) bsum[t] = woff + x - s;   // exclusive
}

__global__ void scan3_k(int* __restrict__ rs, const int* __restrict__ bsum, int n1) {
    int i = blockIdx.x * 256 + threadIdx.x;
    if (i < n1) rs[i] += bsum[blockIdx.x >> 2];
}

__global__ void fill_k(const int* __restrict__ src, const int* __restrict__ dst,
                       const int* __restrict__ rs, int* __restrict__ cur,
                       int* __restrict__ csrc, int E) {
    int e = blockIdx.x * 256 + threadIdx.x;
    if (e >= E) return;
    int d = dst[e];
    int p = rs[d] + atomicAdd(&cur[d], 1);
    csrc[p] = src[e];
}

// -------- gather + relu: z[j] = relu(z[j] + sum_{k in row j} m[csrc[k]])
// 4-deep unrolled gather (memory-level parallelism on the index->data chain)
// + XCD swizzle so each XCD's L2 sees a contiguous row range.
__global__ void neighsum_relu_k(const int* __restrict__ rs, const int* __restrict__ csrc,
                                const float* __restrict__ m, float* __restrict__ z,
                                int R, int nb8) {
    int b = (int)(blockIdx.x & 7) * nb8 + (int)(blockIdx.x >> 3);
    int t = threadIdx.x;
    int j = b * 4 + (t >> 6);
    int f = t & 63;
    if (j >= R) return;
    int s = rs[j], e = rs[j + 1];
    float acc = z[(size_t)j * HID + f];
    int k = s;
    for (; k + 4 <= e; k += 4) {
        int s0 = csrc[k], s1 = csrc[k + 1], s2 = csrc[k + 2], s3 = csrc[k + 3];
        float a0 = m[(size_t)s0 * HID + f];
        float a1 = m[(size_t)s1 * HID + f];
        float a2 = m[(size_t)s2 * HID + f];
        float a3 = m[(size_t)s3 * HID + f];
        acc += (a0 + a1) + (a2 + a3);
    }
    for (; k < e; ++k) acc += m[(size_t)csrc[k] * HID + f];
    z[(size_t)j * HID + f] = fmaxf(acc, 0.f);
}

// -------- level-2 fused gather: z2/m2[j] = hU[gu[j]] + hV[gv[j]] + iso2[j]*Wcol128
__global__ void gather2_k(const float* __restrict__ hU1, const float* __restrict__ hV1,
                          const float* __restrict__ hU2, const float* __restrict__ hV2,
                          const int* __restrict__ gu, const int* __restrict__ gv,
                          const float* __restrict__ iso2,
                          const float* __restrict__ W1, const float* __restrict__ W2,
                          float* __restrict__ z2, float* __restrict__ m2, int n2) {
    int idx = blockIdx.x * blockDim.x + threadIdx.x;
    int j = idx >> 6, f = idx & 63;
    if (j >= n2) return;
    int u = gu[j], v = gv[j];
    float is = iso2[j];
    z2[idx] = hU1[u * HID + f] + hV1[v * HID + f] + is * W1[f * 129 + 128];
    m2[idx] = hU2[u * HID + f] + hV2[v * HID + f] + is * W2[f * 129 + 128];
}

// -------- level-3 fused gather (iso3 is one-hot over 4 classes)
__global__ void gather3_k(const float* __restrict__ hA1, const float* __restrict__ hB1,
                          const float* __restrict__ hC1,
                          const float* __restrict__ hA2, const float* __restrict__ hB2,
                          const float* __restrict__ hC2,
                          const int* __restrict__ ga, const int* __restrict__ gb,
                          const int* __restrict__ gc, const float* __restrict__ iso3,
                          const float* __restrict__ W1, const float* __restrict__ W2,
                          float* __restrict__ z3, float* __restrict__ m3, int n3) {
    int idx = blockIdx.x * blockDim.x + threadIdx.x;
    int j = idx >> 6, f = idx & 63;
    if (j >= n3) return;
    int a = ga[j], b = gb[j], c = gc[j];
    float i0 = iso3[j * 4 + 0], i1 = iso3[j * 4 + 1], i2 = iso3[j * 4 + 2], i3 = iso3[j * 4 + 3];
    float z = hA1[a * HID + f] + hB1[b * HID + f] + hC1[c * HID + f];
    z += i0 * W1[f * 196 + 192] + i1 * W1[f * 196 + 193] + i2 * W1[f * 196 + 194] + i3 * W1[f * 196 + 195];
    float m = hA2[a * HID + f] + hB2[b * HID + f] + hC2[c * HID + f];
    m += i0 * W2[f * 196 + 192] + i1 * W2[f * 196 + 193] + i2 * W2[f * 196 + 194] + i3 * W2[f * 196 + 195];
    z3[idx] = z;
    m3[idx] = m;
}

// -------- split segment sum: grid = G*S blocks, 64 threads; partials via atomicAdd
__global__ void segsum_split_k(const float* __restrict__ h, float* __restrict__ comb,
                               int per, int coloff, int S, int chunk) {
    int b = blockIdx.x;
    int g = b / S, s = b % S;
    int f = threadIdx.x;   // 64 threads
    int r0 = s * chunk;
    int r1 = min(per, r0 + chunk);
    float acc = 0.f;
    const float* p = h + ((size_t)g * per + r0) * HID + f;
    for (int r = r0; r < r1; ++r) { acc += *p; p += HID; }
    atomicAdd(&comb[g * 192 + coloff + f], acc);
}

// -------- classifier: hid = relu(comb@cW1^T + cb1); out = hid@cW2^T + cb2
__global__ void classifier_k(const float* __restrict__ comb,
                             const float* __restrict__ cW1, const float* __restrict__ cb1,
                             const float* __restrict__ cW2, const float* __restrict__ cb2,
                             float* __restrict__ out) {
    __shared__ float row[192];
    __shared__ float hid[64];
    int g = blockIdx.x, t = threadIdx.x;   // 64 threads
    for (int i = t; i < 192; i += 64) row[i] = comb[g * 192 + i];
    __syncthreads();
    float acc = cb1[t];
#pragma unroll 8
    for (int k = 0; k < 192; ++k) acc += row[k] * cW1[t * 192 + k];
    hid[t] = fmaxf(acc, 0.f);
    __syncthreads();
    if (t < 10) {
        float o = cb2[t];
#pragma unroll
        for (int k = 0; k < 64; ++k) o += hid[k] * cW2[t * 64 + k];
        out[g * 10 + t] = o;
    }
}

static inline int cdiv(long long a, long long b) { return (int)((a + b - 1) / b); }

extern "C" void kernel_launch(void* const* d_in, const int* in_sizes, int n_in,
                              void* d_out, int out_size, void* d_ws, size_t ws_size,
                              hipStream_t stream) {
    const float* x        = (const float*)d_in[0];
    const int*   eidx     = (const int*)d_in[1];
    const int*   gu2      = (const int*)d_in[3];
    const int*   gv2      = (const int*)d_in[4];
    const float* iso2     = (const float*)d_in[5];
    const int*   tedges   = (const int*)d_in[6];
    const int*   ga3      = (const int*)d_in[8];
    const int*   gb3      = (const int*)d_in[9];
    const int*   gc3      = (const int*)d_in[10];
    const float* iso3     = (const float*)d_in[11];
    const int*   hedges   = (const int*)d_in[12];
    const float* g1W1[3]  = {(const float*)d_in[14], (const float*)d_in[16], (const float*)d_in[18]};
    const float* g1W2[3]  = {(const float*)d_in[15], (const float*)d_in[17], (const float*)d_in[19]};
    const float* g2W1_0   = (const float*)d_in[20];
    const float* g2W2_0   = (const float*)d_in[21];
    const float* g2W1_1   = (const float*)d_in[22];
    const float* g2W2_1   = (const float*)d_in[23];
    const float* g3W1_0   = (const float*)d_in[24];
    const float* g3W2_0   = (const float*)d_in[25];
    const float* g3W1_1   = (const float*)d_in[26];
    const float* g3W2_1   = (const float*)d_in[27];
    const float* cW1      = (const float*)d_in[28];
    const float* cb1      = (const float*)d_in[29];
    const float* cW2      = (const float*)d_in[30];
    const float* cb2      = (const float*)d_in[31];
    float* out = (float*)d_out;

    const int N  = in_sizes[0] / 32;       // 2560
    const int E1 = in_sizes[1] / 2;
    const int n2 = in_sizes[3];            // 24320
    const int E2 = in_sizes[6] / 2;
    const int n3 = in_sizes[8];            // 145920
    const int E3 = in_sizes[12] / 2;
    const int G  = out_size / 10;          // 128
    const int per1 = N / G, per2 = n2 / G, per3 = n3 / G;

    // ---- workspace carve-up
    float* ws = (float*)d_ws;
    size_t off = 0;
    auto alloc = [&](size_t n) { float* p = ws + off; off += n; return p; };
    const size_t NH = (size_t)N * HID;
    float* nb0 = alloc(NH); float* nb1 = alloc(NH); float* nb2 = alloc(NH);
    float* hU1 = alloc(NH); float* hV1 = alloc(NH); float* hU2 = alloc(NH); float* hV2 = alloc(NH);
    float* hA1 = alloc(NH); float* hB1 = alloc(NH); float* hC1 = alloc(NH);
    float* hA2 = alloc(NH); float* hB2 = alloc(NH); float* hC2 = alloc(NH);
    float* z2 = alloc((size_t)n2 * HID); float* m2 = alloc((size_t)n2 * HID);
    float* z3 = alloc((size_t)n3 * HID); float* m3 = alloc((size_t)n3 * HID);
    float* comb = alloc((size_t)G * 192);
    // int workspace (CSR structures)
    int* iws = (int*)(ws + off);
    size_t ioff = 0;
    auto ialloc = [&](size_t n) { int* p = iws + ioff; ioff += n; return p; };
    int* rs1 = ialloc(N + 1);  int* cur1 = ialloc(N);  int* csrc1 = ialloc(E1);
    int* rs2 = ialloc(n2 + 1); int* cur2 = ialloc(n2); int* csrc2 = ialloc(E2);
    int* rs3 = ialloc(n3 + 1); int* cur3 = ialloc(n3); int* csrc3 = ialloc(E3);
    int* bsum = ialloc(256);
    (void)ws_size;

    dim3 B256(256);
    auto gemm2 = [&](const float* in, const float* Wa, const float* Wb,
                     float* oa, float* ob, int R, int K, int ldw, int coloff) {
        int waves = cdiv(R, RPW);
        int blocks = cdiv(waves, 4);
        if (K == 64)
            gemm2_reg<64><<<blocks, B256, 0, stream>>>(in, Wa, Wb, oa, ob, R, ldw, coloff);
        else
            gemm2_reg<32><<<blocks, B256, 0, stream>>>(in, Wa, Wb, oa, ob, R, ldw, coloff);
    };
    auto build_csr = [&](const int* edges, int E, int R, int* rs, int* cnt, int* csrc) {
        zero_k<<<cdiv(R, 256), B256, 0, stream>>>(cnt, R);
        hist_k<<<cdiv(E, 256), B256, 0, stream>>>(edges + E, cnt, E);
        int n1 = R + 1;
        int nb = cdiv(n1, 1024);
        scan1_k<<<nb, B256, 0, stream>>>(cnt, rs, bsum, n1, R);
        scan2_k<<<1, B256, 0, stream>>>(bsum, nb);
        scan3_k<<<cdiv(n1, 256), B256, 0, stream>>>(rs, bsum, n1);
        zero_k<<<cdiv(R, 256), B256, 0, stream>>>(cnt, R);
        fill_k<<<cdiv(E, 256), B256, 0, stream>>>(edges, edges + E, rs, cnt, csrc, E);
    };
    auto neigh = [&](const int* rs, const int* csrc, const float* m, float* z, int R) {
        int nb = cdiv(R, 4);                 // 4 rows per block (4 waves)
        int nb8 = cdiv(nb, 8);
        neighsum_relu_k<<<nb8 * 8, B256, 0, stream>>>(rs, csrc, m, z, R, nb8);
    };
    auto segsum = [&](const float* h, int per, int coloff) {
        int chunk = 64;
        int S = cdiv(per, chunk);
        segsum_split_k<<<G * S, 64, 0, stream>>>(h, comb, per, coloff, S, chunk);
    };

    // comb accumulated via atomics -> must start at zero (ws is poisoned)
    zero_f<<<cdiv(G * 192, 256), B256, 0, stream>>>(comb, G * 192);

    // ---- build all CSRs up front (reused across layers within a level)
    build_csr(eidx,   E1, N,  rs1, cur1, csrc1);
    build_csr(tedges, E2, n2, rs2, cur2, csrc2);
    build_csr(hedges, E3, n3, rs3, cur3, csrc3);

    // ================= level 1: node GNN (3 layers) =================
    const float* hcur = x;
    float* bufs[3] = {nb0, nb1, nb2};
    for (int l = 0; l < 3; ++l) {
        int K = (l == 0) ? 32 : 64;
        float* z = bufs[l % 3];
        float* m = bufs[(l + 1) % 3];
        gemm2(hcur, g1W1[l], g1W2[l], z, m, N, K, K, 0);
        neigh(rs1, csrc1, m, z, N);
        hcur = z;
    }
    const float* h = hcur;   // final node features (nb2)

    segsum(h, per1, 0);

    // ================= level 2: pair GNN (2 layers) =================
    gemm2(h, g2W1_0, g2W2_0, hU1, hU2, N, 64, 129, 0);
    gemm2(h, g2W1_0, g2W2_0, hV1, hV2, N, 64, 129, 64);
    gather2_k<<<cdiv((long long)n2 * 64, 256), B256, 0, stream>>>(
        hU1, hV1, hU2, hV2, gu2, gv2, iso2, g2W1_0, g2W2_0, z2, m2, n2);
    neigh(rs2, csrc2, m2, z2, n2);
    // layer 1 (in-place on z2; each wave reads its rows before writing)
    gemm2(z2, g2W1_1, g2W2_1, z2, m2, n2, 64, 64, 0);
    neigh(rs2, csrc2, m2, z2, n2);
    segsum(z2, per2, 64);

    // ================= level 3: triple GNN (2 layers) =================
    gemm2(h, g3W1_0, g3W2_0, hA1, hA2, N, 64, 196, 0);
    gemm2(h, g3W1_0, g3W2_0, hB1, hB2, N, 64, 196, 64);
    gemm2(h, g3W1_0, g3W2_0, hC1, hC2, N, 64, 196, 128);
    gather3_k<<<cdiv((long long)n3 * 64, 256), B256, 0, stream>>>(
        hA1, hB1, hC1, hA2, hB2, hC2, ga3, gb3, gc3, iso3, g3W1_0, g3W2_0, z3, m3, n3);
    neigh(rs3, csrc3, m3, z3, n3);
    // layer 1 (in-place on z3)
    gemm2(z3, g3W1_1, g3W2_1, z3, m3, n3, 64, 64, 0);
    neigh(rs3, csrc3, m3, z3, n3);
    segsum(z3, per3, 128);

    // ================= classifier =================
    classifier_k<<<G, 64, 0, stream>>>(comb, cW1, cb1, cW2, cb2, out);
}

// Round 7
// 741.331 us; speedup vs baseline: 1.3170x; 1.3170x over previous
//
#include <hip/hip_runtime.h>
#include <hip/hip_bf16.h>

#define HID 64
#define RPW 16   // rows per wave in gemm2_reg
#define KCH 16   // k-chunk width (W regs live at a time = 2*KCH)

// -------- fused dual GEMM, K-chunked register tiling.
// outa[R][64] = in[R][K] @ Wa[:, coloff:coloff+K]^T ; same for outb/Wb.
// Wa/Wb row-major (64 x ldw). Each wave owns 16 rows: all 16 row-vectors
// loaded up front (lane k holds in[j][k]), W streams in 16-wide k-chunks
// (32 VGPRs live), row values broadcast via v_readlane.
// CRITICAL: `#pragma unroll 1` on the kc loop — R6 fully unrolled it, hoisted
// all 128 W-loads, blew past the 128-VGPR cap and spilled (FETCH 25->240MB).
// In-place safe (outa may alias in): all loads precede all stores per wave.
template <int KC>
__global__ __launch_bounds__(256, 4)
void gemm2_reg(const float* in,
               const float* __restrict__ Wa, const float* __restrict__ Wb,
               float* __restrict__ outa, float* __restrict__ outb,
               int R, int ldw, int coloff) {
    int lane = threadIdx.x & 63;
    int wid = blockIdx.x * (blockDim.x >> 6) + (threadIdx.x >> 6);
    int j0 = wid * RPW;
    if (j0 >= R) return;
    float rv[RPW];
#pragma unroll
    for (int r = 0; r < RPW; ++r) {
        int j = j0 + r;
        rv[r] = (j < R && lane < KC) ? in[(size_t)j * KC + lane] : 0.f;
    }
    float accx[RPW], accy[RPW];
#pragma unroll
    for (int r = 0; r < RPW; ++r) { accx[r] = 0.f; accy[r] = 0.f; }
    const float* pa = Wa + (size_t)lane * ldw + coloff;
    const float* pb = Wb + (size_t)lane * ldw + coloff;
#pragma unroll 1
    for (int kc = 0; kc < KC; kc += KCH) {
        float wx[KCH], wy[KCH];
#pragma unroll
        for (int kk = 0; kk < KCH; ++kk) { wx[kk] = pa[kc + kk]; wy[kk] = pb[kc + kk]; }
#pragma unroll
        for (int r = 0; r < RPW; ++r) {
            float rvr = rv[r];
#pragma unroll
            for (int kk = 0; kk < KCH; ++kk) {
                float s = __int_as_float(__builtin_amdgcn_ds_bpermute(
                              (kc + kk) << 2, __float_as_int(rvr)));
                accx[r] = fmaf(s, wx[kk], accx[r]);
                accy[r] = fmaf(s, wy[kk], accy[r]);
            }
        }
    }
#pragma unroll
    for (int r = 0; r < RPW; ++r) {
        int j = j0 + r;
        if (j < R) {
            outa[(size_t)j * HID + lane] = accx[r];
            outb[(size_t)j * HID + lane] = accy[r];
        }
    }
}

// ======== CSR build (per edge set, indexed by dst) ========
__global__ void zero_k(int* __restrict__ p, int n) {
    int i = blockIdx.x * 256 + threadIdx.x;
    if (i < n) p[i] = 0;
}

__global__ void zero_f(float* __restrict__ p, int n) {
    int i = blockIdx.x * 256 + threadIdx.x;
    if (i < n) p[i] = 0.f;
}

__global__ void hist_k(const int* __restrict__ dst, int* __restrict__ cnt, int E) {
    int e = blockIdx.x * 256 + threadIdx.x;
    if (e < E) atomicAdd(&cnt[dst[e]], 1);
}

// exclusive scan over n1 = n+1 virtual entries (cnt has n entries; entry n = 0)
__global__ void scan1_k(const int* __restrict__ cnt, int* __restrict__ rs,
                        int* __restrict__ bsum, int n1, int n) {
    __shared__ int wsum[4];
    int t = threadIdx.x;
    int base = blockIdx.x * 1024 + t * 4;
    int v[4]; int s = 0;
#pragma unroll
    for (int i = 0; i < 4; ++i) { int idx = base + i; v[i] = s; s += (idx < n) ? cnt[idx] : 0; }
    int lane = t & 63, wv = t >> 6;
    int x = s;
#pragma unroll
    for (int off = 1; off < 64; off <<= 1) { int y = __shfl_up(x, off, 64); if (lane >= off) x += y; }
    if (lane == 63) wsum[wv] = x;
    __syncthreads();
    int woff = 0;
    for (int w = 0; w < wv; ++w) woff += wsum[w];
    int excl = woff + (x - s);
#pragma unroll
    for (int i = 0; i < 4; ++i) { int idx = base + i; if (idx < n1) rs[idx] = excl + v[i]; }
    if (t == 255) bsum[blockIdx.x] = wsum[0] + wsum[1] + wsum[2] + wsum[3];
}

__global__ void scan2_k(int* __restrict__ bsum, int nb) {
    __shared__ int wsum[4];
    int t = threadIdx.x;
    int s = (t < nb) ? bsum[t] : 0;
    int lane = t & 63, wv = t >> 6;
    int x = s;
#pragma unroll
    for (int off = 1; off < 64; off <<= 1) { int y = __shfl_up(x, off, 64); if (lane >= off) x += y; }
    if (lane == 63) wsum[wv] = x;
    __syncthreads();
    int woff = 0;
    for (int w = 0; w < wv; ++w) woff += wsum[w];
    if (t < nb) bsum[t] = woff + x - s;   // exclusive
}

__global__ void scan3_k(int* __restrict__ rs, const int* __restrict__ bsum, int n1) {
    int i = blockIdx.x * 256 + threadIdx.x;
    if (i < n1) rs[i] += bsum[blockIdx.x >> 2];
}

__global__ void fill_k(const int* __restrict__ src, const int* __restrict__ dst,
                       const int* __restrict__ rs, int* __restrict__ cur,
                       int* __restrict__ csrc, int E) {
    int e = blockIdx.x * 256 + threadIdx.x;
    if (e >= E) return;
    int d = dst[e];
    int p = rs[d] + atomicAdd(&cur[d], 1);
    csrc[p] = src[e];
}

// -------- gather + relu: z[j] = relu(z[j] + sum_{k in row j} m[csrc[k]])
__global__ void neighsum_relu_k(const int* __restrict__ rs, const int* __restrict__ csrc,
                                const float* __restrict__ m, float* __restrict__ z,
                                int R, int nb8) {
    int b = (int)(blockIdx.x & 7) * nb8 + (int)(blockIdx.x >> 3);
    int t = threadIdx.x;
    int j = b * 4 + (t >> 6);
    int f = t & 63;
    if (j >= R) return;
    int s = rs[j], e = rs[j + 1];
    float acc = z[(size_t)j * HID + f];
    int k = s;
    for (; k + 4 <= e; k += 4) {
        int s0 = csrc[k], s1 = csrc[k + 1], s2 = csrc[k + 2], s3 = csrc[k + 3];
        float a0 = m[(size_t)s0 * HID + f];
        float a1 = m[(size_t)s1 * HID + f];
        float a2 = m[(size_t)s2 * HID + f];
        float a3 = m[(size_t)s3 * HID + f];
        acc += (a0 + a1) + (a2 + a3);
    }
    for (; k < e; ++k) acc += m[(size_t)csrc[k] * HID + f];
    z[(size_t)j * HID + f] = fmaxf(acc, 0.f);
}

// -------- level-2 fused gather
__global__ void gather2_k(const float* __restrict__ hU1, const float* __restrict__ hV1,
                          const float* __restrict__ hU2, const float* __restrict__ hV2,
                          const int* __restrict__ gu, const int* __restrict__ gv,
                          const float* __restrict__ iso2,
                          const float* __restrict__ W1, const float* __restrict__ W2,
                          float* __restrict__ z2, float* __restrict__ m2, int n2) {
    int idx = blockIdx.x * blockDim.x + threadIdx.x;
    int j = idx >> 6, f = idx & 63;
    if (j >= n2) return;
    int u = gu[j], v = gv[j];
    float is = iso2[j];
    z2[idx] = hU1[u * HID + f] + hV1[v * HID + f] + is * W1[f * 129 + 128];
    m2[idx] = hU2[u * HID + f] + hV2[v * HID + f] + is * W2[f * 129 + 128];
}

// -------- level-3 fused gather (iso3 is one-hot over 4 classes)
__global__ void gather3_k(const float* __restrict__ hA1, const float* __restrict__ hB1,
                          const float* __restrict__ hC1,
                          const float* __restrict__ hA2, const float* __restrict__ hB2,
                          const float* __restrict__ hC2,
                          const int* __restrict__ ga, const int* __restrict__ gb,
                          const int* __restrict__ gc, const float* __restrict__ iso3,
                          const float* __restrict__ W1, const float* __restrict__ W2,
                          float* __restrict__ z3, float* __restrict__ m3, int n3) {
    int idx = blockIdx.x * blockDim.x + threadIdx.x;
    int j = idx >> 6, f = idx & 63;
    if (j >= n3) return;
    int a = ga[j], b = gb[j], c = gc[j];
    float i0 = iso3[j * 4 + 0], i1 = iso3[j * 4 + 1], i2 = iso3[j * 4 + 2], i3 = iso3[j * 4 + 3];
    float z = hA1[a * HID + f] + hB1[b * HID + f] + hC1[c * HID + f];
    z += i0 * W1[f * 196 + 192] + i1 * W1[f * 196 + 193] + i2 * W1[f * 196 + 194] + i3 * W1[f * 196 + 195];
    float m = hA2[a * HID + f] + hB2[b * HID + f] + hC2[c * HID + f];
    m += i0 * W2[f * 196 + 192] + i1 * W2[f * 196 + 193] + i2 * W2[f * 196 + 194] + i3 * W2[f * 196 + 195];
    z3[idx] = z;
    m3[idx] = m;
}

// -------- split segment sum
__global__ void segsum_split_k(const float* __restrict__ h, float* __restrict__ comb,
                               int per, int coloff, int S, int chunk) {
    int b = blockIdx.x;
    int g = b / S, s = b % S;
    int f = threadIdx.x;   // 64 threads
    int r0 = s * chunk;
    int r1 = min(per, r0 + chunk);
    float acc = 0.f;
    const float* p = h + ((size_t)g * per + r0) * HID + f;
    for (int r = r0; r < r1; ++r) { acc += *p; p += HID; }
    atomicAdd(&comb[g * 192 + coloff + f], acc);
}

// -------- classifier
__global__ void classifier_k(const float* __restrict__ comb,
                             const float* __restrict__ cW1, const float* __restrict__ cb1,
                             const float* __restrict__ cW2, const float* __restrict__ cb2,
                             float* __restrict__ out) {
    __shared__ float row[192];
    __shared__ float hid[64];
    int g = blockIdx.x, t = threadIdx.x;   // 64 threads
    for (int i = t; i < 192; i += 64) row[i] = comb[g * 192 + i];
    __syncthreads();
    float acc = cb1[t];
#pragma unroll 8
    for (int k = 0; k < 192; ++k) acc += row[k] * cW1[t * 192 + k];
    hid[t] = fmaxf(acc, 0.f);
    __syncthreads();
    if (t < 10) {
        float o = cb2[t];
#pragma unroll
        for (int k = 0; k < 64; ++k) o += hid[k] * cW2[t * 64 + k];
        out[g * 10 + t] = o;
    }
}

static inline int cdiv(long long a, long long b) { return (int)((a + b - 1) / b); }

extern "C" void kernel_launch(void* const* d_in, const int* in_sizes, int n_in,
                              void* d_out, int out_size, void* d_ws, size_t ws_size,
                              hipStream_t stream) {
    const float* x        = (const float*)d_in[0];
    const int*   eidx     = (const int*)d_in[1];
    const int*   gu2      = (const int*)d_in[3];
    const int*   gv2      = (const int*)d_in[4];
    const float* iso2     = (const float*)d_in[5];
    const int*   tedges   = (const int*)d_in[6];
    const int*   ga3      = (const int*)d_in[8];
    const int*   gb3      = (const int*)d_in[9];
    const int*   gc3      = (const int*)d_in[10];
    const float* iso3     = (const float*)d_in[11];
    const int*   hedges   = (const int*)d_in[12];
    const float* g1W1[3]  = {(const float*)d_in[14], (const float*)d_in[16], (const float*)d_in[18]};
    const float* g1W2[3]  = {(const float*)d_in[15], (const float*)d_in[17], (const float*)d_in[19]};
    const float* g2W1_0   = (const float*)d_in[20];
    const float* g2W2_0   = (const float*)d_in[21];
    const float* g2W1_1   = (const float*)d_in[22];
    const float* g2W2_1   = (const float*)d_in[23];
    const float* g3W1_0   = (const float*)d_in[24];
    const float* g3W2_0   = (const float*)d_in[25];
    const float* g3W1_1   = (const float*)d_in[26];
    const float* g3W2_1   = (const float*)d_in[27];
    const float* cW1      = (const float*)d_in[28];
    const float* cb1      = (const float*)d_in[29];
    const float* cW2      = (const float*)d_in[30];
    const float* cb2      = (const float*)d_in[31];
    float* out = (float*)d_out;

    const int N  = in_sizes[0] / 32;       // 2560
    const int E1 = in_sizes[1] / 2;
    const int n2 = in_sizes[3];            // 24320
    const int E2 = in_sizes[6] / 2;
    const int n3 = in_sizes[8];            // 145920
    const int E3 = in_sizes[12] / 2;
    const int G  = out_size / 10;          // 128
    const int per1 = N / G, per2 = n2 / G, per3 = n3 / G;

    // ---- workspace carve-up
    float* ws = (float*)d_ws;
    size_t off = 0;
    auto alloc = [&](size_t n) { float* p = ws + off; off += n; return p; };
    const size_t NH = (size_t)N * HID;
    float* nb0 = alloc(NH); float* nb1 = alloc(NH); float* nb2 = alloc(NH);
    float* hU1 = alloc(NH); float* hV1 = alloc(NH); float* hU2 = alloc(NH); float* hV2 = alloc(NH);
    float* hA1 = alloc(NH); float* hB1 = alloc(NH); float* hC1 = alloc(NH);
    float* hA2 = alloc(NH); float* hB2 = alloc(NH); float* hC2 = alloc(NH);
    float* z2 = alloc((size_t)n2 * HID); float* m2 = alloc((size_t)n2 * HID);
    float* z3 = alloc((size_t)n3 * HID); float* m3 = alloc((size_t)n3 * HID);
    float* comb = alloc((size_t)G * 192);
    // int workspace (CSR structures)
    int* iws = (int*)(ws + off);
    size_t ioff = 0;
    auto ialloc = [&](size_t n) { int* p = iws + ioff; ioff += n; return p; };
    int* rs1 = ialloc(N + 1);  int* cur1 = ialloc(N);  int* csrc1 = ialloc(E1);
    int* rs2 = ialloc(n2 + 1); int* cur2 = ialloc(n2); int* csrc2 = ialloc(E2);
    int* rs3 = ialloc(n3 + 1); int* cur3 = ialloc(n3); int* csrc3 = ialloc(E3);
    int* bsum = ialloc(256);
    (void)ws_size;

    dim3 B256(256);
    auto gemm2 = [&](const float* in, const float* Wa, const float* Wb,
                     float* oa, float* ob, int R, int K, int ldw, int coloff) {
        int waves = cdiv(R, RPW);
        int blocks = cdiv(waves, 4);
        if (K == 64)
            gemm2_reg<64><<<blocks, B256, 0, stream>>>(in, Wa, Wb, oa, ob, R, ldw, coloff);
        else
            gemm2_reg<32><<<blocks, B256, 0, stream>>>(in, Wa, Wb, oa, ob, R, ldw, coloff);
    };
    auto build_csr = [&](const int* edges, int E, int R, int* rs, int* cnt, int* csrc) {
        zero_k<<<cdiv(R, 256), B256, 0, stream>>>(cnt, R);
        hist_k<<<cdiv(E, 256), B256, 0, stream>>>(edges + E, cnt, E);
        int n1 = R + 1;
        int nb = cdiv(n1, 1024);
        scan1_k<<<nb, B256, 0, stream>>>(cnt, rs, bsum, n1, R);
        scan2_k<<<1, B256, 0, stream>>>(bsum, nb);
        scan3_k<<<cdiv(n1, 256), B256, 0, stream>>>(rs, bsum, n1);
        zero_k<<<cdiv(R, 256), B256, 0, stream>>>(cnt, R);
        fill_k<<<cdiv(E, 256), B256, 0, stream>>>(edges, edges + E, rs, cnt, csrc, E);
    };
    auto neigh = [&](const int* rs, const int* csrc, const float* m, float* z, int R) {
        int nb = cdiv(R, 4);                 // 4 rows per block (4 waves)
        int nb8 = cdiv(nb, 8);
        neighsum_relu_k<<<nb8 * 8, B256, 0, stream>>>(rs, csrc, m, z, R, nb8);
    };
    auto segsum = [&](const float* h, int per, int coloff) {
        int chunk = 64;
        int S = cdiv(per, chunk);
        segsum_split_k<<<G * S, 64, 0, stream>>>(h, comb, per, coloff, S, chunk);
    };

    // comb accumulated via atomics -> must start at zero (ws is poisoned)
    zero_f<<<cdiv(G * 192, 256), B256, 0, stream>>>(comb, G * 192);

    // ---- build all CSRs up front (reused across layers within a level)
    build_csr(eidx,   E1, N,  rs1, cur1, csrc1);
    build_csr(tedges, E2, n2, rs2, cur2, csrc2);
    build_csr(hedges, E3, n3, rs3, cur3, csrc3);

    // ================= level 1: node GNN (3 layers) =================
    const float* hcur = x;
    float* bufs[3] = {nb0, nb1, nb2};
    for (int l = 0; l < 3; ++l) {
        int K = (l == 0) ? 32 : 64;
        float* z = bufs[l % 3];
        float* m = bufs[(l + 1) % 3];
        gemm2(hcur, g1W1[l], g1W2[l], z, m, N, K, K, 0);
        neigh(rs1, csrc1, m, z, N);
        hcur = z;
    }
    const float* h = hcur;   // final node features (nb2)

    segsum(h, per1, 0);

    // ================= level 2: pair GNN (2 layers) =================
    gemm2(h, g2W1_0, g2W2_0, hU1, hU2, N, 64, 129, 0);
    gemm2(h, g2W1_0, g2W2_0, hV1, hV2, N, 64, 129, 64);
    gather2_k<<<cdiv((long long)n2 * 64, 256), B256, 0, stream>>>(
        hU1, hV1, hU2, hV2, gu2, gv2, iso2, g2W1_0, g2W2_0, z2, m2, n2);
    neigh(rs2, csrc2, m2, z2, n2);
    // layer 1 (in-place on z2; each wave reads its rows before writing)
    gemm2(z2, g2W1_1, g2W2_1, z2, m2, n2, 64, 64, 0);
    neigh(rs2, csrc2, m2, z2, n2);
    segsum(z2, per2, 64);

    // ================= level 3: triple GNN (2 layers) =================
    gemm2(h, g3W1_0, g3W2_0, hA1, hA2, N, 64, 196, 0);
    gemm2(h, g3W1_0, g3W2_0, hB1, hB2, N, 64, 196, 64);
    gemm2(h, g3W1_0, g3W2_0, hC1, hC2, N, 64, 196, 128);
    gather3_k<<<cdiv((long long)n3 * 64, 256), B256, 0, stream>>>(
        hA1, hB1, hC1, hA2, hB2, hC2, ga3, gb3, gc3, iso3, g3W1_0, g3W2_0, z3, m3, n3);
    neigh(rs3, csrc3, m3, z3, n3);
    // layer 1 (in-place on z3)
    gemm2(z3, g3W1_1, g3W2_1, z3, m3, n3, 64, 64, 0);
    neigh(rs3, csrc3, m3, z3, n3);
    segsum(z3, per3, 128);

    // ================= classifier =================
    classifier_k<<<G, 64, 0, stream>>>(comb, cW1, cb1, cW2, cb2, out);
}

// Round 8
// 600.985 us; speedup vs baseline: 1.6245x; 1.2335x over previous
//
#include <hip/hip_runtime.h>
#include <hip/hip_bf16.h>

#define HID 64
#define RPW 16   // rows per wave in gemm2_reg
#define KCH 8    // k-chunk width (W regs live at a time = 2*KCH)

// -------- fused dual GEMM, K-chunked register tiling.
// outa[R][64] = in[R][K] @ Wa[:, coloff:coloff+K]^T ; same for outb/Wb.
// Wa/Wb row-major (64 x ldw). Each wave owns 16 rows: row-vectors loaded up
// front (lane k holds in[j][k]), W streams in 8-wide k-chunks, row values
// broadcast via v_readlane (SGPR, no DS pipe).
// amdgpu_waves_per_eu(4,4) FORCES 4 waves/EU: launch_bounds' 2nd arg is only
// a minimum-occupancy hint (VGPR cap) — in R5/R7 the allocator chose 8
// waves/EU (64 VGPRs) and spilled (WRITE_SIZE 140MB vs 74 ideal). Exact
// bounds remove the incentive. Live set ~80 VGPRs < 128 budget.
// In-place safe (outa may alias in): all loads precede all stores per wave.
template <int KC>
__global__ __attribute__((amdgpu_flat_work_group_size(256, 256),
                          amdgpu_waves_per_eu(4, 4)))
void gemm2_reg(const float* in,
               const float* __restrict__ Wa, const float* __restrict__ Wb,
               float* __restrict__ outa, float* __restrict__ outb,
               int R, int ldw, int coloff) {
    int lane = threadIdx.x & 63;
    int wid = blockIdx.x * (blockDim.x >> 6) + (threadIdx.x >> 6);
    int j0 = wid * RPW;
    if (j0 >= R) return;
    float rv[RPW];
#pragma unroll
    for (int r = 0; r < RPW; ++r) {
        int j = j0 + r;
        rv[r] = (j < R && lane < KC) ? in[(size_t)j * KC + lane] : 0.f;
    }
    float accx[RPW], accy[RPW];
#pragma unroll
    for (int r = 0; r < RPW; ++r) { accx[r] = 0.f; accy[r] = 0.f; }
    const float* pa = Wa + (size_t)lane * ldw + coloff;
    const float* pb = Wb + (size_t)lane * ldw + coloff;
#pragma unroll 1
    for (int kc = 0; kc < KC; kc += KCH) {
        float wx[KCH], wy[KCH];
#pragma unroll
        for (int kk = 0; kk < KCH; ++kk) { wx[kk] = pa[kc + kk]; wy[kk] = pb[kc + kk]; }
#pragma unroll
        for (int r = 0; r < RPW; ++r) {
            float rvr = rv[r];
#pragma unroll
            for (int kk = 0; kk < KCH; ++kk) {
                float s = __int_as_float(__builtin_amdgcn_readlane(
                              __float_as_int(rvr), kc + kk));
                accx[r] = fmaf(s, wx[kk], accx[r]);
                accy[r] = fmaf(s, wy[kk], accy[r]);
            }
        }
    }
#pragma unroll
    for (int r = 0; r < RPW; ++r) {
        int j = j0 + r;
        if (j < R) {
            outa[(size_t)j * HID + lane] = accx[r];
            outb[(size_t)j * HID + lane] = accy[r];
        }
    }
}

// ======== CSR build (per edge set, indexed by dst) ========
__global__ void zero_k(int* __restrict__ p, int n) {
    int i = blockIdx.x * 256 + threadIdx.x;
    if (i < n) p[i] = 0;
}

__global__ void zero_f(float* __restrict__ p, int n) {
    int i = blockIdx.x * 256 + threadIdx.x;
    if (i < n) p[i] = 0.f;
}

__global__ void hist_k(const int* __restrict__ dst, int* __restrict__ cnt, int E) {
    int e = blockIdx.x * 256 + threadIdx.x;
    if (e < E) atomicAdd(&cnt[dst[e]], 1);
}

// exclusive scan over n1 = n+1 virtual entries (cnt has n entries; entry n = 0)
__global__ void scan1_k(const int* __restrict__ cnt, int* __restrict__ rs,
                        int* __restrict__ bsum, int n1, int n) {
    __shared__ int wsum[4];
    int t = threadIdx.x;
    int base = blockIdx.x * 1024 + t * 4;
    int v[4]; int s = 0;
#pragma unroll
    for (int i = 0; i < 4; ++i) { int idx = base + i; v[i] = s; s += (idx < n) ? cnt[idx] : 0; }
    int lane = t & 63, wv = t >> 6;
    int x = s;
#pragma unroll
    for (int off = 1; off < 64; off <<= 1) { int y = __shfl_up(x, off, 64); if (lane >= off) x += y; }
    if (lane == 63) wsum[wv] = x;
    __syncthreads();
    int woff = 0;
    for (int w = 0; w < wv; ++w) woff += wsum[w];
    int excl = woff + (x - s);
#pragma unroll
    for (int i = 0; i < 4; ++i) { int idx = base + i; if (idx < n1) rs[idx] = excl + v[i]; }
    if (t == 255) bsum[blockIdx.x] = wsum[0] + wsum[1] + wsum[2] + wsum[3];
}

__global__ void scan2_k(int* __restrict__ bsum, int nb) {
    __shared__ int wsum[4];
    int t = threadIdx.x;
    int s = (t < nb) ? bsum[t] : 0;
    int lane = t & 63, wv = t >> 6;
    int x = s;
#pragma unroll
    for (int off = 1; off < 64; off <<= 1) { int y = __shfl_up(x, off, 64); if (lane >= off) x += y; }
    if (lane == 63) wsum[wv] = x;
    __syncthreads();
    int woff = 0;
    for (int w = 0; w < wv; ++w) woff += wsum[w];
    if (t < nb) bsum[t] = woff + x - s;   // exclusive
}

__global__ void scan3_k(int* __restrict__ rs, const int* __restrict__ bsum, int n1) {
    int i = blockIdx.x * 256 + threadIdx.x;
    if (i < n1) rs[i] += bsum[blockIdx.x >> 2];
}

__global__ void fill_k(const int* __restrict__ src, const int* __restrict__ dst,
                       const int* __restrict__ rs, int* __restrict__ cur,
                       int* __restrict__ csrc, int E) {
    int e = blockIdx.x * 256 + threadIdx.x;
    if (e >= E) return;
    int d = dst[e];
    int p = rs[d] + atomicAdd(&cur[d], 1);
    csrc[p] = src[e];
}

// -------- gather + relu: z[j] = relu(z[j] + sum_{k in row j} m[csrc[k]])
__global__ void neighsum_relu_k(const int* __restrict__ rs, const int* __restrict__ csrc,
                                const float* __restrict__ m, float* __restrict__ z,
                                int R, int nb8) {
    int b = (int)(blockIdx.x & 7) * nb8 + (int)(blockIdx.x >> 3);
    int t = threadIdx.x;
    int j = b * 4 + (t >> 6);
    int f = t & 63;
    if (j >= R) return;
    int s = rs[j], e = rs[j + 1];
    float acc = z[(size_t)j * HID + f];
    int k = s;
    for (; k + 4 <= e; k += 4) {
        int s0 = csrc[k], s1 = csrc[k + 1], s2 = csrc[k + 2], s3 = csrc[k + 3];
        float a0 = m[(size_t)s0 * HID + f];
        float a1 = m[(size_t)s1 * HID + f];
        float a2 = m[(size_t)s2 * HID + f];
        float a3 = m[(size_t)s3 * HID + f];
        acc += (a0 + a1) + (a2 + a3);
    }
    for (; k < e; ++k) acc += m[(size_t)csrc[k] * HID + f];
    z[(size_t)j * HID + f] = fmaxf(acc, 0.f);
}

// -------- level-2 fused gather
__global__ void gather2_k(const float* __restrict__ hU1, const float* __restrict__ hV1,
                          const float* __restrict__ hU2, const float* __restrict__ hV2,
                          const int* __restrict__ gu, const int* __restrict__ gv,
                          const float* __restrict__ iso2,
                          const float* __restrict__ W1, const float* __restrict__ W2,
                          float* __restrict__ z2, float* __restrict__ m2, int n2) {
    int idx = blockIdx.x * blockDim.x + threadIdx.x;
    int j = idx >> 6, f = idx & 63;
    if (j >= n2) return;
    int u = gu[j], v = gv[j];
    float is = iso2[j];
    z2[idx] = hU1[u * HID + f] + hV1[v * HID + f] + is * W1[f * 129 + 128];
    m2[idx] = hU2[u * HID + f] + hV2[v * HID + f] + is * W2[f * 129 + 128];
}

// -------- level-3 fused gather (iso3 is one-hot over 4 classes)
__global__ void gather3_k(const float* __restrict__ hA1, const float* __restrict__ hB1,
                          const float* __restrict__ hC1,
                          const float* __restrict__ hA2, const float* __restrict__ hB2,
                          const float* __restrict__ hC2,
                          const int* __restrict__ ga, const int* __restrict__ gb,
                          const int* __restrict__ gc, const float* __restrict__ iso3,
                          const float* __restrict__ W1, const float* __restrict__ W2,
                          float* __restrict__ z3, float* __restrict__ m3, int n3) {
    int idx = blockIdx.x * blockDim.x + threadIdx.x;
    int j = idx >> 6, f = idx & 63;
    if (j >= n3) return;
    int a = ga[j], b = gb[j], c = gc[j];
    float i0 = iso3[j * 4 + 0], i1 = iso3[j * 4 + 1], i2 = iso3[j * 4 + 2], i3 = iso3[j * 4 + 3];
    float z = hA1[a * HID + f] + hB1[b * HID + f] + hC1[c * HID + f];
    z += i0 * W1[f * 196 + 192] + i1 * W1[f * 196 + 193] + i2 * W1[f * 196 + 194] + i3 * W1[f * 196 + 195];
    float m = hA2[a * HID + f] + hB2[b * HID + f] + hC2[c * HID + f];
    m += i0 * W2[f * 196 + 192] + i1 * W2[f * 196 + 193] + i2 * W2[f * 196 + 194] + i3 * W2[f * 196 + 195];
    z3[idx] = z;
    m3[idx] = m;
}

// -------- split segment sum
__global__ void segsum_split_k(const float* __restrict__ h, float* __restrict__ comb,
                               int per, int coloff, int S, int chunk) {
    int b = blockIdx.x;
    int g = b / S, s = b % S;
    int f = threadIdx.x;   // 64 threads
    int r0 = s * chunk;
    int r1 = min(per, r0 + chunk);
    float acc = 0.f;
    const float* p = h + ((size_t)g * per + r0) * HID + f;
    for (int r = r0; r < r1; ++r) { acc += *p; p += HID; }
    atomicAdd(&comb[g * 192 + coloff + f], acc);
}

// -------- classifier
__global__ void classifier_k(const float* __restrict__ comb,
                             const float* __restrict__ cW1, const float* __restrict__ cb1,
                             const float* __restrict__ cW2, const float* __restrict__ cb2,
                             float* __restrict__ out) {
    __shared__ float row[192];
    __shared__ float hid[64];
    int g = blockIdx.x, t = threadIdx.x;   // 64 threads
    for (int i = t; i < 192; i += 64) row[i] = comb[g * 192 + i];
    __syncthreads();
    float acc = cb1[t];
#pragma unroll 8
    for (int k = 0; k < 192; ++k) acc += row[k] * cW1[t * 192 + k];
    hid[t] = fmaxf(acc, 0.f);
    __syncthreads();
    if (t < 10) {
        float o = cb2[t];
#pragma unroll
        for (int k = 0; k < 64; ++k) o += hid[k] * cW2[t * 64 + k];
        out[g * 10 + t] = o;
    }
}

static inline int cdiv(long long a, long long b) { return (int)((a + b - 1) / b); }

extern "C" void kernel_launch(void* const* d_in, const int* in_sizes, int n_in,
                              void* d_out, int out_size, void* d_ws, size_t ws_size,
                              hipStream_t stream) {
    const float* x        = (const float*)d_in[0];
    const int*   eidx     = (const int*)d_in[1];
    const int*   gu2      = (const int*)d_in[3];
    const int*   gv2      = (const int*)d_in[4];
    const float* iso2     = (const float*)d_in[5];
    const int*   tedges   = (const int*)d_in[6];
    const int*   ga3      = (const int*)d_in[8];
    const int*   gb3      = (const int*)d_in[9];
    const int*   gc3      = (const int*)d_in[10];
    const float* iso3     = (const float*)d_in[11];
    const int*   hedges   = (const int*)d_in[12];
    const float* g1W1[3]  = {(const float*)d_in[14], (const float*)d_in[16], (const float*)d_in[18]};
    const float* g1W2[3]  = {(const float*)d_in[15], (const float*)d_in[17], (const float*)d_in[19]};
    const float* g2W1_0   = (const float*)d_in[20];
    const float* g2W2_0   = (const float*)d_in[21];
    const float* g2W1_1   = (const float*)d_in[22];
    const float* g2W2_1   = (const float*)d_in[23];
    const float* g3W1_0   = (const float*)d_in[24];
    const float* g3W2_0   = (const float*)d_in[25];
    const float* g3W1_1   = (const float*)d_in[26];
    const float* g3W2_1   = (const float*)d_in[27];
    const float* cW1      = (const float*)d_in[28];
    const float* cb1      = (const float*)d_in[29];
    const float* cW2      = (const float*)d_in[30];
    const float* cb2      = (const float*)d_in[31];
    float* out = (float*)d_out;

    const int N  = in_sizes[0] / 32;       // 2560
    const int E1 = in_sizes[1] / 2;
    const int n2 = in_sizes[3];            // 24320
    const int E2 = in_sizes[6] / 2;
    const int n3 = in_sizes[8];            // 145920
    const int E3 = in_sizes[12] / 2;
    const int G  = out_size / 10;          // 128
    const int per1 = N / G, per2 = n2 / G, per3 = n3 / G;

    // ---- workspace carve-up
    float* ws = (float*)d_ws;
    size_t off = 0;
    auto alloc = [&](size_t n) { float* p = ws + off; off += n; return p; };
    const size_t NH = (size_t)N * HID;
    float* nb0 = alloc(NH); float* nb1 = alloc(NH); float* nb2 = alloc(NH);
    float* hU1 = alloc(NH); float* hV1 = alloc(NH); float* hU2 = alloc(NH); float* hV2 = alloc(NH);
    float* hA1 = alloc(NH); float* hB1 = alloc(NH); float* hC1 = alloc(NH);
    float* hA2 = alloc(NH); float* hB2 = alloc(NH); float* hC2 = alloc(NH);
    float* z2 = alloc((size_t)n2 * HID); float* m2 = alloc((size_t)n2 * HID);
    float* z3 = alloc((size_t)n3 * HID); float* m3 = alloc((size_t)n3 * HID);
    float* comb = alloc((size_t)G * 192);
    // int workspace (CSR structures)
    int* iws = (int*)(ws + off);
    size_t ioff = 0;
    auto ialloc = [&](size_t n) { int* p = iws + ioff; ioff += n; return p; };
    int* rs1 = ialloc(N + 1);  int* cur1 = ialloc(N);  int* csrc1 = ialloc(E1);
    int* rs2 = ialloc(n2 + 1); int* cur2 = ialloc(n2); int* csrc2 = ialloc(E2);
    int* rs3 = ialloc(n3 + 1); int* cur3 = ialloc(n3); int* csrc3 = ialloc(E3);
    int* bsum = ialloc(256);
    (void)ws_size;

    dim3 B256(256);
    auto gemm2 = [&](const float* in, const float* Wa, const float* Wb,
                     float* oa, float* ob, int R, int K, int ldw, int coloff) {
        int waves = cdiv(R, RPW);
        int blocks = cdiv(waves, 4);
        if (K == 64)
            gemm2_reg<64><<<blocks, B256, 0, stream>>>(in, Wa, Wb, oa, ob, R, ldw, coloff);
        else
            gemm2_reg<32><<<blocks, B256, 0, stream>>>(in, Wa, Wb, oa, ob, R, ldw, coloff);
    };
    auto build_csr = [&](const int* edges, int E, int R, int* rs, int* cnt, int* csrc) {
        zero_k<<<cdiv(R, 256), B256, 0, stream>>>(cnt, R);
        hist_k<<<cdiv(E, 256), B256, 0, stream>>>(edges + E, cnt, E);
        int n1 = R + 1;
        int nb = cdiv(n1, 1024);
        scan1_k<<<nb, B256, 0, stream>>>(cnt, rs, bsum, n1, R);
        scan2_k<<<1, B256, 0, stream>>>(bsum, nb);
        scan3_k<<<cdiv(n1, 256), B256, 0, stream>>>(rs, bsum, n1);
        zero_k<<<cdiv(R, 256), B256, 0, stream>>>(cnt, R);
        fill_k<<<cdiv(E, 256), B256, 0, stream>>>(edges, edges + E, rs, cnt, csrc, E);
    };
    auto neigh = [&](const int* rs, const int* csrc, const float* m, float* z, int R) {
        int nb = cdiv(R, 4);                 // 4 rows per block (4 waves)
        int nb8 = cdiv(nb, 8);
        neighsum_relu_k<<<nb8 * 8, B256, 0, stream>>>(rs, csrc, m, z, R, nb8);
    };
    auto segsum = [&](const float* h, int per, int coloff) {
        int chunk = 64;
        int S = cdiv(per, chunk);
        segsum_split_k<<<G * S, 64, 0, stream>>>(h, comb, per, coloff, S, chunk);
    };

    // comb accumulated via atomics -> must start at zero (ws is poisoned)
    zero_f<<<cdiv(G * 192, 256), B256, 0, stream>>>(comb, G * 192);

    // ---- build all CSRs up front (reused across layers within a level)
    build_csr(eidx,   E1, N,  rs1, cur1, csrc1);
    build_csr(tedges, E2, n2, rs2, cur2, csrc2);
    build_csr(hedges, E3, n3, rs3, cur3, csrc3);

    // ================= level 1: node GNN (3 layers) =================
    const float* hcur = x;
    float* bufs[3] = {nb0, nb1, nb2};
    for (int l = 0; l < 3; ++l) {
        int K = (l == 0) ? 32 : 64;
        float* z = bufs[l % 3];
        float* m = bufs[(l + 1) % 3];
        gemm2(hcur, g1W1[l], g1W2[l], z, m, N, K, K, 0);
        neigh(rs1, csrc1, m, z, N);
        hcur = z;
    }
    const float* h = hcur;   // final node features (nb2)

    segsum(h, per1, 0);

    // ================= level 2: pair GNN (2 layers) =================
    gemm2(h, g2W1_0, g2W2_0, hU1, hU2, N, 64, 129, 0);
    gemm2(h, g2W1_0, g2W2_0, hV1, hV2, N, 64, 129, 64);
    gather2_k<<<cdiv((long long)n2 * 64, 256), B256, 0, stream>>>(
        hU1, hV1, hU2, hV2, gu2, gv2, iso2, g2W1_0, g2W2_0, z2, m2, n2);
    neigh(rs2, csrc2, m2, z2, n2);
    // layer 1 (in-place on z2; each wave reads its rows before writing)
    gemm2(z2, g2W1_1, g2W2_1, z2, m2, n2, 64, 64, 0);
    neigh(rs2, csrc2, m2, z2, n2);
    segsum(z2, per2, 64);

    // ================= level 3: triple GNN (2 layers) =================
    gemm2(h, g3W1_0, g3W2_0, hA1, hA2, N, 64, 196, 0);
    gemm2(h, g3W1_0, g3W2_0, hB1, hB2, N, 64, 196, 64);
    gemm2(h, g3W1_0, g3W2_0, hC1, hC2, N, 64, 196, 128);
    gather3_k<<<cdiv((long long)n3 * 64, 256), B256, 0, stream>>>(
        hA1, hB1, hC1, hA2, hB2, hC2, ga3, gb3, gc3, iso3, g3W1_0, g3W2_0, z3, m3, n3);
    neigh(rs3, csrc3, m3, z3, n3);
    // layer 1 (in-place on z3)
    gemm2(z3, g3W1_1, g3W2_1, z3, m3, n3, 64, 64, 0);
    neigh(rs3, csrc3, m3, z3, n3);
    segsum(z3, per3, 128);

    // ================= classifier =================
    classifier_k<<<G, 64, 0, stream>>>(comb, cW1, cb1, cW2, cb2, out);
}